// Round 1
// baseline (549.444 us; speedup 1.0000x reference)
//
#include <hip/hip_runtime.h>

#define D_DIM 1024
#define NROW  8192

typedef short bf16x8 __attribute__((ext_vector_type(8)));
typedef float f32x4  __attribute__((ext_vector_type(4)));

typedef const __attribute__((address_space(1))) void g_void;
typedef __attribute__((address_space(3))) void lds_void;

__device__ __forceinline__ void gload16(const void* g, void* l) {
    __builtin_amdgcn_global_load_lds((g_void*)g, (lds_void*)l, 16, 0, 0);
}

__device__ __forceinline__ unsigned short f2bf(float f) {
    unsigned int b = __float_as_uint(f);
    unsigned int r = (b + 0x7FFFu + ((b >> 16) & 1u)) >> 16;
    return (unsigned short)r;
}

// One block per row: fp32 -> bf16 conversion + fp32 row sum-of-squares.
__global__ __launch_bounds__(256) void mk_conv(const float* __restrict__ src,
                                               unsigned short* __restrict__ dst,
                                               float* __restrict__ rowsq,
                                               float* out, int zero_out) {
    const int row = blockIdx.x;
    const int tid = threadIdx.x;
    const float4* s4 = (const float4*)(src + (size_t)row * D_DIM);
    float4 v = s4[tid];
    ushort4 o;
    o.x = f2bf(v.x); o.y = f2bf(v.y); o.z = f2bf(v.z); o.w = f2bf(v.w);
    ((ushort4*)(dst + (size_t)row * D_DIM))[tid] = o;
    float ss = v.x * v.x + v.y * v.y + v.z * v.z + v.w * v.w;
#pragma unroll
    for (int off = 32; off; off >>= 1) ss += __shfl_down(ss, off);
    __shared__ float red[4];
    if ((tid & 63) == 0) red[tid >> 6] = ss;
    __syncthreads();
    if (tid == 0) rowsq[row] = red[0] + red[1] + red[2] + red[3];
    if (zero_out && row == 0 && tid == 0) out[0] = 0.0f;
}

// Fused multi-kernel-MMD GEMM: 128x128 tile, 4 waves, 16x16x32 bf16 MFMA,
// global_load_lds staging with XOR-swizzled LDS, fused exp epilogue + reduce.
__global__ __launch_bounds__(256) void mk_gemm(const unsigned short* __restrict__ Sb,
                                               const unsigned short* __restrict__ Tb,
                                               const float* __restrict__ s2,
                                               const float* __restrict__ t2,
                                               float* __restrict__ out) {
    __shared__ __align__(16) char smem[32768];  // A: [0,16K), B: [16K,32K)
    __shared__ float red[4];

    const int bid = blockIdx.x;
    const int m   = bid >> 12;        // 0:SS 1:ST 2:TT  (4096 tiles per matrix)
    const int t   = bid & 4095;
    const int ti  = t >> 6, tj = t & 63;

    const unsigned short* Abf = (m == 2) ? Tb : Sb;
    const unsigned short* Bbf = (m == 0) ? Sb : Tb;
    const float* x2a = (m == 2) ? t2 : s2;
    const float* x2b = (m == 0) ? s2 : t2;

    const int rowA0 = ti * 128;
    const int colB0 = tj * 128;

    const int tid  = threadIdx.x;
    const int w    = tid >> 6, lane = tid & 63;
    const int wr   = w >> 1, wc = w & 1;

    // ---- staging addressing (global_load_lds writes dst + lane*16 linearly;
    //      pre-swizzle the GLOBAL source so LDS holds the XOR-swizzled tile) ----
    const int lrow = lane >> 3;                    // row within 8-row segment
    const int kb   = ((lane & 7) ^ lrow) << 4;     // swizzled source byte in 128B row
    const size_t rowBytes = (size_t)D_DIM * 2;

    const char* aSrc = (const char*)Abf + (size_t)(rowA0 + w * 32 + lrow) * rowBytes + kb;
    const char* bSrc = (const char*)Bbf + (size_t)(colB0 + w * 32 + lrow) * rowBytes + kb;
    char* aDst = smem + w * 4096;
    char* bDst = smem + 16384 + w * 4096;

    // ---- fragment read addressing (swizzled ds_read_b128) ----
    const int frow = lane & 15;
    const int fgrp = lane >> 4;
    const int xorv = (frow & 7) << 4;
    int aRowOff[4], bRowOff[4];
#pragma unroll
    for (int i = 0; i < 4; ++i) {
        aRowOff[i] = (wr * 64 + i * 16 + frow) * 128;
        bRowOff[i] = 16384 + (wc * 64 + i * 16 + frow) * 128;
    }

    f32x4 acc[4][4] = {};

    for (int kt = 0; kt < 16; ++kt) {
        const char* as = aSrc + kt * 128;
        const char* bs = bSrc + kt * 128;
#pragma unroll
        for (int n = 0; n < 4; ++n) {
            gload16(as + (size_t)n * 8 * rowBytes, aDst + n * 1024);
            gload16(bs + (size_t)n * 8 * rowBytes, bDst + n * 1024);
        }
        __syncthreads();   // drains vmcnt before barrier (compiler-inserted)
#pragma unroll
        for (int ks = 0; ks < 2; ++ks) {
            const int ub = ks * 64 + fgrp * 16;
            bf16x8 av[4], bv[4];
#pragma unroll
            for (int i = 0; i < 4; ++i)
                av[i] = *(const bf16x8*)(smem + aRowOff[i] + (ub ^ xorv));
#pragma unroll
            for (int i = 0; i < 4; ++i)
                bv[i] = *(const bf16x8*)(smem + bRowOff[i] + (ub ^ xorv));
#pragma unroll
            for (int mi = 0; mi < 4; ++mi)
#pragma unroll
                for (int ni = 0; ni < 4; ++ni)
                    acc[mi][ni] = __builtin_amdgcn_mfma_f32_16x16x32_bf16(
                        av[mi], bv[ni], acc[mi][ni], 0, 0, 0);
        }
        __syncthreads();
    }

    // ---- fused epilogue: d2 -> sum over 6 bandwidths of exp(-d2/bw) ----
    // C/D layout (verified m89/m91): col = lane&15, row = (lane>>4)*4 + reg
    float lsum = 0.0f;
    const int grb = rowA0 + wr * 64 + fgrp * 4;
    const int gcb = colB0 + wc * 64 + frow;
#pragma unroll
    for (int ni = 0; ni < 4; ++ni) {
        const int gc   = gcb + ni * 16;
        const float y2 = x2b[gc];
#pragma unroll
        for (int mi = 0; mi < 4; ++mi) {
            f32x4 v = acc[mi][ni];
#pragma unroll
            for (int r = 0; r < 4; ++r) {
                const int gr = grb + mi * 16 + r;
                float d2 = x2a[gr] + y2 - 2.0f * v[r];
                d2 = fmaxf(d2, 0.0f);
                // t = exp(-d2/100); bandwidths {100,50,20,10,5,1} -> t^{1,2,5,10,20,100}
                float t1   = __expf(d2 * -0.01f);
                float t2v  = t1 * t1;
                float t4   = t2v * t2v;
                float t5   = t4 * t1;
                float t10  = t5 * t5;
                float t20  = t10 * t10;
                float t40  = t20 * t20;
                float t80  = t40 * t40;
                float t100 = t80 * t20;
                float ksum = t1 + t2v + t5 + t10 + t20 + t100;
                // exact diagonal: d2 == 0 analytically; bf16 cancellation would
                // otherwise inject ~2e-5 into the loss
                if (m != 1 && gr == gc) ksum = 6.0f;
                lsum += ksum;
            }
        }
    }

#pragma unroll
    for (int off = 32; off; off >>= 1) lsum += __shfl_down(lsum, off);
    if (lane == 0) red[w] = lsum;
    __syncthreads();
    if (tid == 0) {
        const float wgt = (m == 1) ? -2.0f : 1.0f;
        // loss = (S_ss - 2*S_st + S_tt) / (6 * 8192 * 8192)
        atomicAdd(out, (red[0] + red[1] + red[2] + red[3]) * (wgt / 402653184.0f));
    }
}

extern "C" void kernel_launch(void* const* d_in, const int* in_sizes, int n_in,
                              void* d_out, int out_size, void* d_ws, size_t ws_size,
                              hipStream_t stream) {
    const float* src = (const float*)d_in[0];
    const float* tgt = (const float*)d_in[1];
    float* out = (float*)d_out;

    unsigned short* Sb = (unsigned short*)d_ws;
    unsigned short* Tb = Sb + (size_t)NROW * D_DIM;
    float* s2 = (float*)(Tb + (size_t)NROW * D_DIM);
    float* t2 = s2 + NROW;

    mk_conv<<<NROW, 256, 0, stream>>>(src, Sb, s2, out, 1);
    mk_conv<<<NROW, 256, 0, stream>>>(tgt, Tb, t2, out, 0);
    mk_gemm<<<3 * 64 * 64, 256, 0, stream>>>(Sb, Tb, s2, t2, out);
}

// Round 2
// 358.774 us; speedup vs baseline: 1.5314x; 1.5314x over previous
//
#include <hip/hip_runtime.h>

#define D_DIM 1024
#define NROW  8192
#define ROWB  2048      // bytes per bf16 row

typedef short bf16x8 __attribute__((ext_vector_type(8)));
typedef float f32x4  __attribute__((ext_vector_type(4)));

typedef const __attribute__((address_space(1))) void g_void;
typedef __attribute__((address_space(3))) void lds_void;

__device__ __forceinline__ void gload16(const void* g, void* l) {
    __builtin_amdgcn_global_load_lds((g_void*)g, (lds_void*)l, 16, 0, 0);
}

__device__ __forceinline__ unsigned short f2bf(float f) {
    unsigned int b = __float_as_uint(f);
    unsigned int r = (b + 0x7FFFu + ((b >> 16) & 1u)) >> 16;
    return (unsigned short)r;
}

// One block per row: fp32 -> bf16 conversion + fp32 row sum-of-squares.
__global__ __launch_bounds__(256) void mk_conv(const float* __restrict__ src,
                                               unsigned short* __restrict__ dst,
                                               float* __restrict__ rowsq,
                                               float* out, int zero_out) {
    const int row = blockIdx.x;
    const int tid = threadIdx.x;
    const float4* s4 = (const float4*)(src + (size_t)row * D_DIM);
    float4 v = s4[tid];
    ushort4 o;
    o.x = f2bf(v.x); o.y = f2bf(v.y); o.z = f2bf(v.z); o.w = f2bf(v.w);
    ((ushort4*)(dst + (size_t)row * D_DIM))[tid] = o;
    float ss = v.x * v.x + v.y * v.y + v.z * v.z + v.w * v.w;
#pragma unroll
    for (int off = 32; off; off >>= 1) ss += __shfl_down(ss, off);
    __shared__ float red[4];
    if ((tid & 63) == 0) red[tid >> 6] = ss;
    __syncthreads();
    if (tid == 0) rowsq[row] = red[0] + red[1] + red[2] + red[3];
    if (zero_out && row == 0 && tid == 0) out[0] = 0.0f;
}

// 256x256-tile fused MK-MMD GEMM. 8 waves (2Mx4N), 16x16x32 bf16 MFMA.
// Ring of 4 K-half slots (BK=32), 2 phases per K-half, counted vmcnt(8),
// setprio around MFMA clusters, conflict-free paired-row XOR LDS layout.
// Symmetric matrices (SS/TT) computed upper-triangular with weight 2.
__global__ __launch_bounds__(512) void mk_gemm(const unsigned short* __restrict__ Sb,
                                               const unsigned short* __restrict__ Tb,
                                               const float* __restrict__ s2,
                                               const float* __restrict__ t2,
                                               float* __restrict__ out) {
    // LDS: A slots [0,64K): slot*16384 ; B slots [64K,128K): 65536+slot*16384
    __shared__ __align__(16) char smem[131072];
    __shared__ float red[8];

    const int bid = blockIdx.x;
    int m, ti, tj;
    if (bid < 1056) {                      // SS (528) then TT (528), ti<=tj
        m = (bid < 528) ? 0 : 2;
        int s = (bid < 528) ? bid : bid - 528;
        int t = 0;
        while (s >= 32 - t) { s -= 32 - t; ++t; }
        ti = t; tj = t + s;
    } else {                               // ST: full 32x32
        m = 1; int s = bid - 1056; ti = s >> 5; tj = s & 31;
    }

    const unsigned short* Abf = (m == 2) ? Tb : Sb;
    const unsigned short* Bbf = (m == 0) ? Sb : Tb;
    const float* x2a = (m == 2) ? t2 : s2;
    const float* x2b = (m == 0) ? s2 : t2;

    const int rowA0 = ti * 256, colB0 = tj * 256;

    const int tid = threadIdx.x;
    const int w = tid >> 6, lane = tid & 63;
    const int wr = w >> 2, wc = w & 3;     // wave grid 2M x 4N

    // ---- staging addressing (pre-swizzled global source, linear LDS dest) ----
    // LDS byte l (in 16KB slot): row = 2*(l>>7) + ((l>>6)&1), sb=(l>>4)&3
    // content[row][sb] = global[row][ kh*32 + (sb ^ ((row>>1)&3))*8 .. ]
    const int rowc  = 2 * (w * 8 + (lane >> 3)) + ((lane >> 2) & 1);
    const int ssb   = ((lane & 3) ^ ((lane >> 3) & 3)) << 4;
    const char* aS0 = (const char*)Abf + (size_t)(rowA0 + rowc) * ROWB + ssb;
    const char* bS0 = (const char*)Bbf + (size_t)(colB0 + rowc) * ROWB + ssb;
    char* ldsA = smem + w * 1024;          // + slot*16384 (+8192 for 2nd instr)
    char* ldsB = smem + 65536 + w * 1024;

    // ---- fragment read addressing (swizzled ds_read_b128) ----
    const int frow = lane & 15, fgrp = lane >> 4;
    const int rb   = (frow >> 1);
    const int xsb  = (fgrp ^ (rb & 3)) << 4;
    const int aRB  = (wr * 64 + rb) * 128 + (frow & 1) * 64 + xsb;
    const int bRB  = 65536 + (wc * 32 + rb) * 128 + (frow & 1) * 64 + xsb;

    f32x4 acc[8][4] = {};

#define STAGE_A(khv, slot) do {                                            \
    const size_t ko_ = (size_t)(khv) * 64;                                 \
    gload16(aS0 + ko_,          ldsA + (slot) * 16384);                    \
    gload16(aS0 + ko_ + 262144, ldsA + (slot) * 16384 + 8192);             \
} while (0)
#define STAGE_B(khv, slot) do {                                            \
    const size_t ko_ = (size_t)(khv) * 64;                                 \
    gload16(bS0 + ko_,          ldsB + (slot) * 16384);                    \
    gload16(bS0 + ko_ + 262144, ldsB + (slot) * 16384 + 8192);             \
} while (0)

    // prologue: stage K-halves 0,1,2 into slots 0,1,2
    STAGE_A(0, 0); STAGE_B(0, 0);
    STAGE_A(1, 1); STAGE_B(1, 1);
    STAGE_A(2, 2); STAGE_B(2, 2);
    asm volatile("s_waitcnt vmcnt(8)" ::: "memory");   // kh0 landed (kh1,kh2 fly)
    __builtin_amdgcn_s_barrier();
    __builtin_amdgcn_sched_barrier(0);

    for (int g = 0; g < 8; ++g) {
#pragma unroll
        for (int j = 0; j < 4; ++j) {                  // kh = 4g+j, slot = j
            const int sA = j * 16384;
            const int sT = ((j + 3) & 3);              // target slot for kh+3
            const int kh = 4 * g + j;
            bf16x8 av[8], bv[4];
            // ================= phase A: ni 0..1 =================
#pragma unroll
            for (int mi = 0; mi < 8; ++mi)
                av[mi] = *(const bf16x8*)(smem + sA + aRB + mi * 1024);
            bv[0] = *(const bf16x8*)(smem + sA + bRB);
            bv[1] = *(const bf16x8*)(smem + sA + bRB + 1024);
            if (g < 7 || j == 0) STAGE_A(kh + 3, sT);
            __builtin_amdgcn_s_barrier();
            asm volatile("s_waitcnt lgkmcnt(0)" ::: "memory");
            __builtin_amdgcn_sched_barrier(0);
            __builtin_amdgcn_s_setprio(1);
#pragma unroll
            for (int ni = 0; ni < 2; ++ni)
#pragma unroll
                for (int mi = 0; mi < 8; ++mi)
                    acc[mi][ni] = __builtin_amdgcn_mfma_f32_16x16x32_bf16(
                        av[mi], bv[ni], acc[mi][ni], 0, 0, 0);
            __builtin_amdgcn_s_setprio(0);
            __builtin_amdgcn_sched_barrier(0);
            __builtin_amdgcn_s_barrier();
            __builtin_amdgcn_sched_barrier(0);
            // ================= phase B: ni 2..3 =================
            bv[2] = *(const bf16x8*)(smem + sA + bRB + 2048);
            bv[3] = *(const bf16x8*)(smem + sA + bRB + 3072);
            if (g < 7 || j == 0) STAGE_B(kh + 3, sT);
            // counted vmcnt: publish landing of kh+1 (epilogue drains 8->4->0)
            if (j == 0)      { asm volatile("s_waitcnt vmcnt(8)" ::: "memory"); }
            else if (j == 1) { if (g < 7) asm volatile("s_waitcnt vmcnt(8)" ::: "memory");
                               else       asm volatile("s_waitcnt vmcnt(4)" ::: "memory"); }
            else             { if (g < 7) asm volatile("s_waitcnt vmcnt(8)" ::: "memory");
                               else       asm volatile("s_waitcnt vmcnt(0)" ::: "memory"); }
            __builtin_amdgcn_s_barrier();
            asm volatile("s_waitcnt lgkmcnt(0)" ::: "memory");
            __builtin_amdgcn_sched_barrier(0);
            __builtin_amdgcn_s_setprio(1);
#pragma unroll
            for (int ni = 2; ni < 4; ++ni)
#pragma unroll
                for (int mi = 0; mi < 8; ++mi)
                    acc[mi][ni] = __builtin_amdgcn_mfma_f32_16x16x32_bf16(
                        av[mi], bv[ni], acc[mi][ni], 0, 0, 0);
            __builtin_amdgcn_s_setprio(0);
            __builtin_amdgcn_sched_barrier(0);
            __builtin_amdgcn_s_barrier();
            __builtin_amdgcn_sched_barrier(0);
        }
    }

    // ---- fused epilogue: d2 -> sum over 6 bandwidths of exp(-d2/bw) ----
    // C/D layout: col = lane&15 (B row), row = (lane>>4)*4 + reg (A row)
    float lsum = 0.0f;
    const int grb = rowA0 + wr * 128 + fgrp * 4;
    const int gcb = colB0 + wc * 64 + frow;
#pragma unroll
    for (int ni = 0; ni < 4; ++ni) {
        const int gc   = gcb + ni * 16;
        const float y2 = x2b[gc];
#pragma unroll
        for (int mi = 0; mi < 8; ++mi) {
            f32x4 v = acc[mi][ni];
#pragma unroll
            for (int r = 0; r < 4; ++r) {
                const int gr = grb + mi * 16 + r;
                float d2 = fmaxf(x2a[gr] + y2 - 2.0f * v[r], 0.0f);
                // t = exp(-d2/100); bandwidths {100,50,20,10,5,1} -> t^{1,2,5,10,20,100}
                float t1   = __expf(d2 * -0.01f);
                float t2v  = t1 * t1;
                float t4   = t2v * t2v;
                float t5   = t4 * t1;
                float t10  = t5 * t5;
                float t20  = t10 * t10;
                float t40  = t20 * t20;
                float t80  = t40 * t40;
                float t100 = t80 * t20;
                float ksum = t1 + t2v + t5 + t10 + t20 + t100;
                if (m != 1 && gr == gc) ksum = 6.0f;   // exact diagonal
                lsum += ksum;
            }
        }
    }

#pragma unroll
    for (int off = 32; off; off >>= 1) lsum += __shfl_down(lsum, off);
    __syncthreads();
    if (lane == 0) red[w] = lsum;
    __syncthreads();
    if (tid == 0) {
        float wgt = (m == 1) ? -2.0f : ((ti == tj) ? 1.0f : 2.0f);
        float tot = 0.0f;
#pragma unroll
        for (int i = 0; i < 8; ++i) tot += red[i];
        // loss = (S_ss - 2*S_st + S_tt) / (6 * 8192 * 8192)
        atomicAdd(out, tot * (wgt / 402653184.0f));
    }
}

extern "C" void kernel_launch(void* const* d_in, const int* in_sizes, int n_in,
                              void* d_out, int out_size, void* d_ws, size_t ws_size,
                              hipStream_t stream) {
    const float* src = (const float*)d_in[0];
    const float* tgt = (const float*)d_in[1];
    float* out = (float*)d_out;

    unsigned short* Sb = (unsigned short*)d_ws;
    unsigned short* Tb = Sb + (size_t)NROW * D_DIM;
    float* s2 = (float*)(Tb + (size_t)NROW * D_DIM);
    float* t2 = s2 + NROW;

    mk_conv<<<NROW, 256, 0, stream>>>(src, Sb, s2, out, 1);
    mk_conv<<<NROW, 256, 0, stream>>>(tgt, Tb, t2, out, 0);
    mk_gemm<<<2080, 512, 0, stream>>>(Sb, Tb, s2, t2, out);
}